// Round 5
// baseline (541.901 us; speedup 1.0000x reference)
//
#include <hip/hip_runtime.h>
#include <math.h>

#define NHEADS 16
#define HD 64
#define HID 1024
#define BATCH 4
#define SQ 16
#define SKV 8192
#define ROWS 64     // B*SQ
#define NCHUNK 32
#define CHUNK 256   // keys per attn block
#define NT (CHUNK / 16)
#define LN_EPS 1e-5f

// ---------------------------------------------------------------------------
// DPP rotate-reduce: sum across the 16 lanes of each 16-lane row.
// ---------------------------------------------------------------------------
__device__ __forceinline__ float rowsum16(float x) {
    union fi { float f; int i; };
    fi a, b;
    a.f = x;
    b.i = __builtin_amdgcn_update_dpp(0, a.i, 0x128, 0xf, 0xf, true); a.f += b.f; // ror 8
    b.i = __builtin_amdgcn_update_dpp(0, a.i, 0x124, 0xf, 0xf, true); a.f += b.f; // ror 4
    b.i = __builtin_amdgcn_update_dpp(0, a.i, 0x122, 0xf, 0xf, true); a.f += b.f; // ror 2
    b.i = __builtin_amdgcn_update_dpp(0, a.i, 0x121, 0xf, 0xf, true); a.f += b.f; // ror 1
    return a.f;
}

// ---------------------------------------------------------------------------
// Kernel 1: q = RoPE(x @ wq^T + bq) -> [B][NH][SQ][HD]  (unchanged)
// ---------------------------------------------------------------------------
__global__ __launch_bounds__(256) void qrope_gemv(
    const float* __restrict__ x,
    const float* __restrict__ xm,
    const float* __restrict__ wq,
    const float* __restrict__ bq,
    float* __restrict__ qout)
{
    __shared__ float xs[ROWS * 256];
    __shared__ float sqx[4][ROWS];

    const int t = threadIdx.x, w = t >> 6, l = t & 63;
    const int cb = blockIdx.x;
    const int h = cb >> 4;
    const int sub = cb & 15;
    const int dd = sub * 2 + (w & 1) + (w >> 1) * 32;
    const int j = h * 64 + dd;

    float acc[ROWS];
    #pragma unroll
    for (int r = 0; r < ROWS; ++r) acc[r] = 0.f;

    const float4* x4 = (const float4*)x;
    const float4* w4 = (const float4*)(wq + (size_t)j * HID);
    float4* xs4 = (float4*)xs;

    for (int ck = 0; ck < 4; ++ck) {
        __syncthreads();
        #pragma unroll
        for (int p = 0; p < 16; ++p) {
            const int idx = t + p * 256;
            const int r = idx >> 6, c = idx & 63;
            xs4[idx] = x4[(size_t)r * 256 + ck * 64 + c];
        }
        __syncthreads();

        const float4 wf = w4[ck * 64 + l];
        #pragma unroll
        for (int r = 0; r < ROWS; ++r) {
            const float4 xf = xs4[r * 64 + l];
            acc[r] += wf.x * xf.x + wf.y * xf.y + wf.z * xf.z + wf.w * xf.w;
        }
    }

    #pragma unroll
    for (int r = 0; r < ROWS; ++r) {
        float a = acc[r];
        #pragma unroll
        for (int off = 32; off; off >>= 1) a += __shfl_xor(a, off);
        acc[r] = a;
    }
    float val = acc[0];
    #pragma unroll
    for (int r = 1; r < ROWS; ++r) val = (l == r) ? acc[r] : val;
    val += bq[j];

    sqx[w][l] = val;
    __syncthreads();

    const int r = l;
    float outv;
    if (w < 2) {
        const float q0 = sqx[w][l];
        const float q1 = sqx[w + 2][l];
        const float sn = xm[r * 64 + dd];
        const float co = xm[r * 64 + 32 + dd];
        outv = q0 * co - q1 * sn;
    } else {
        const int d2 = dd - 32;
        const float q0 = sqx[w - 2][l];
        const float q1 = sqx[w][l];
        const float sn = xm[r * 64 + d2];
        const float co = xm[r * 64 + 32 + d2];
        outv = q0 * sn + q1 * co;
    }
    const int b = r >> 4, s_ = r & 15;
    qout[(((size_t)b * NHEADS + h) * SQ + s_) * HD + dd] = outv;
}

// ---------------------------------------------------------------------------
// Kernel 2: barrier-free zero-LDS partial attention with explicit register
// double-buffer prefetch + deferred (uniform-branch) softmax rescale.
// grid (NCHUNK, NH, B) = 2048 blocks, 256 threads (4 independent waves).
// Lane l = (kg = l>>4, dq = l&15): dims 4dq..4dq+3, keys {16st + 4ki + kg}.
// ---------------------------------------------------------------------------
#define LOADKV(kr, vr, st_)                          \
    {                                                \
        _Pragma("unroll")                            \
        for (int ki = 0; ki < 4; ++ki) {             \
            const int key = (st_) * 16 + ki * 4 + kg;\
            kr[ki] = kb[key * 16 + dq];              \
            vr[ki] = vb[key * 16 + dq];              \
        }                                            \
    }

#define BODY(kr, vr)                                                          \
    {                                                                         \
        _Pragma("unroll")                                                     \
        for (int c = 0; c < 4; ++c) {                                         \
            float pk[4];                                                      \
            _Pragma("unroll")                                                 \
            for (int ki = 0; ki < 4; ++ki) {                                  \
                const float d = kr[ki].x * qreg[c].x + kr[ki].y * qreg[c].y   \
                              + kr[ki].z * qreg[c].z + kr[ki].w * qreg[c].w;  \
                pk[ki] = rowsum16(d);                                         \
            }                                                                 \
            float mx = fmaxf(fmaxf(pk[0], pk[1]), fmaxf(pk[2], pk[3]));       \
            mx = fmaxf(mx, __shfl_xor(mx, 16));                               \
            mx = fmaxf(mx, __shfl_xor(mx, 32));                               \
            if (mx > m[c]) {   /* wave-uniform branch */                      \
                const float scale = __expf(m[c] - mx);                        \
                m[c] = mx;                                                    \
                lsum[c] *= scale;                                             \
                oacc[c].x *= scale; oacc[c].y *= scale;                       \
                oacc[c].z *= scale; oacc[c].w *= scale;                       \
            }                                                                 \
            _Pragma("unroll")                                                 \
            for (int ki = 0; ki < 4; ++ki) {                                  \
                const float pe = __expf(pk[ki] - m[c]);                       \
                lsum[c] += pe;                                                \
                oacc[c].x += pe * vr[ki].x;                                   \
                oacc[c].y += pe * vr[ki].y;                                   \
                oacc[c].z += pe * vr[ki].z;                                   \
                oacc[c].w += pe * vr[ki].w;                                   \
            }                                                                 \
        }                                                                     \
    }

__global__ __launch_bounds__(256, 4) void attn_partial(
    const float* __restrict__ q,     // [B][NH][SQ][HD]
    const float* __restrict__ kc,    // [B][NH][SKV][HD]
    const float* __restrict__ vc,    // [B][NH][SKV][HD]
    float* __restrict__ o_part,      // [B*NH][NCHUNK][SQ][HD]
    float* __restrict__ ml_part)     // [B*NH][NCHUNK][SQ][2]
{
    const int chunk = blockIdx.x, h = blockIdx.y, b = blockIdx.z;
    const int bh = b * NHEADS + h;
    const int t = threadIdx.x, w = t >> 6, l = t & 63;
    const int kg = l >> 4, dq = l & 15;

    const float4* qb = (const float4*)(q + (size_t)bh * SQ * HD);
    const float4* kb = (const float4*)(kc + (size_t)bh * SKV * HD + (size_t)chunk * CHUNK * HD);
    const float4* vb = (const float4*)(vc + (size_t)bh * SKV * HD + (size_t)chunk * CHUNK * HD);

    float4 qreg[4];
    #pragma unroll
    for (int c = 0; c < 4; ++c) qreg[c] = qb[(4 * w + c) * 16 + dq];

    float4 oacc[4];
    float m[4], lsum[4];
    #pragma unroll
    for (int c = 0; c < 4; ++c) {
        oacc[c] = make_float4(0.f, 0.f, 0.f, 0.f);
        m[c] = -INFINITY;
        lsum[c] = 0.f;
    }

    float4 kA[4], vA[4], kB[4], vB[4];
    LOADKV(kA, vA, 0);

    for (int st2 = 0; st2 < NT / 2; ++st2) {
        const int st = st2 * 2;
        LOADKV(kB, vB, st + 1);        // prefetch next subtile (st+1 <= NT-1)
        BODY(kA, vA);
        if (st2 < NT / 2 - 1) LOADKV(kA, vA, st + 2);
        BODY(kB, vB);
    }

    // ---- final reduce over the 4 kg groups (lane bits 4,5)
    #pragma unroll
    for (int c = 0; c < 4; ++c) {
        #pragma unroll
        for (int off = 16; off <= 32; off <<= 1) {
            oacc[c].x += __shfl_xor(oacc[c].x, off);
            oacc[c].y += __shfl_xor(oacc[c].y, off);
            oacc[c].z += __shfl_xor(oacc[c].z, off);
            oacc[c].w += __shfl_xor(oacc[c].w, off);
            lsum[c] += __shfl_xor(lsum[c], off);
        }
    }

    if (kg == 0) {
        #pragma unroll
        for (int c = 0; c < 4; ++c) {
            const int qi = 4 * w + c;
            ((float4*)(o_part + (((size_t)bh * NCHUNK + chunk) * SQ + qi) * HD))[dq] = oacc[c];
        }
    }
    if (l == 0) {
        #pragma unroll
        for (int c = 0; c < 4; ++c) {
            const int qi = 4 * w + c;
            ml_part[(((size_t)bh * NCHUNK + chunk) * SQ + qi) * 2 + 0] = m[c];
            ml_part[(((size_t)bh * NCHUNK + chunk) * SQ + qi) * 2 + 1] = lsum[c];
        }
    }
}

// ---------------------------------------------------------------------------
// Kernel 3: combine partials -> ctx [64][1024]  (unchanged)
// ---------------------------------------------------------------------------
__global__ __launch_bounds__(256) void attn_combine(
    const float* __restrict__ o_part,
    const float* __restrict__ ml_part,
    float* __restrict__ ctx)
{
    __shared__ float mls[NCHUNK * 4 * 2];
    const int bh = blockIdx.x >> 2, qg = blockIdx.x & 3;
    const int b = bh >> 4, h = bh & 15;
    const int t = threadIdx.x;
    const int qi_l = t >> 6, d = t & 63;
    const int qi = qg * 4 + qi_l;

    mls[t] = ml_part[(((size_t)bh * NCHUNK + (t >> 3)) * SQ + qg * 4 + ((t >> 1) & 3)) * 2 + (t & 1)];
    __syncthreads();

    float M = -INFINITY;
    #pragma unroll
    for (int c = 0; c < NCHUNK; ++c) M = fmaxf(M, mls[(c * 4 + qi_l) * 2]);
    float L = 0.f, O = 0.f;
    #pragma unroll 4
    for (int c = 0; c < NCHUNK; ++c) {
        const float sc = __expf(mls[(c * 4 + qi_l) * 2] - M);
        L += mls[(c * 4 + qi_l) * 2 + 1] * sc;
        O += o_part[(((size_t)bh * NCHUNK + c) * SQ + qi) * HD + d] * sc;
    }
    ctx[((size_t)(b * SQ + qi)) * HID + h * HD + d] = O / L;
}

// ---------------------------------------------------------------------------
// Kernel 4: y = x + ctx @ wo^T + bo  (unchanged)
// ---------------------------------------------------------------------------
__global__ __launch_bounds__(256) void out_gemv(
    const float* __restrict__ ctx,
    const float* __restrict__ x,
    const float* __restrict__ wo,
    const float* __restrict__ bo,
    float* __restrict__ y)
{
    __shared__ float xs[ROWS * 256];

    const int t = threadIdx.x, w = t >> 6, l = t & 63;
    const int j = blockIdx.x * 4 + w;

    float acc[ROWS];
    #pragma unroll
    for (int r = 0; r < ROWS; ++r) acc[r] = 0.f;

    const float4* c4 = (const float4*)ctx;
    const float4* w4 = (const float4*)(wo + (size_t)j * HID);
    float4* xs4 = (float4*)xs;

    for (int ck = 0; ck < 4; ++ck) {
        __syncthreads();
        #pragma unroll
        for (int p = 0; p < 16; ++p) {
            const int idx = t + p * 256;
            const int r = idx >> 6, c = idx & 63;
            xs4[idx] = c4[(size_t)r * 256 + ck * 64 + c];
        }
        __syncthreads();

        const float4 wf = w4[ck * 64 + l];
        #pragma unroll
        for (int r = 0; r < ROWS; ++r) {
            const float4 xf = xs4[r * 64 + l];
            acc[r] += wf.x * xf.x + wf.y * xf.y + wf.z * xf.z + wf.w * xf.w;
        }
    }

    #pragma unroll
    for (int r = 0; r < ROWS; ++r) {
        float a = acc[r];
        #pragma unroll
        for (int off = 32; off; off >>= 1) a += __shfl_xor(a, off);
        acc[r] = a;
    }
    float val = acc[0];
    #pragma unroll
    for (int r = 1; r < ROWS; ++r) val = (l == r) ? acc[r] : val;

    val += bo[j] + x[(size_t)l * HID + j];
    y[(size_t)l * HID + j] = val;
}

// ---------------------------------------------------------------------------
// Kernel 5: out = LN(y) * gamma + beta  (unchanged)
// ---------------------------------------------------------------------------
__global__ __launch_bounds__(256) void ln_kernel(
    const float* __restrict__ y,
    const float* __restrict__ gamma,
    const float* __restrict__ beta,
    float* __restrict__ out)
{
    __shared__ float red[8];
    const int r = blockIdx.x, t = threadIdx.x;
    const int w = t >> 6, l = t & 63;

    const float4 yv = ((const float4*)(y + (size_t)r * HID))[t];
    float sum = yv.x + yv.y + yv.z + yv.w;
    float ssq = yv.x * yv.x + yv.y * yv.y + yv.z * yv.z + yv.w * yv.w;
    #pragma unroll
    for (int off = 32; off; off >>= 1) {
        sum += __shfl_xor(sum, off);
        ssq += __shfl_xor(ssq, off);
    }
    if (l == 0) { red[w] = sum; red[4 + w] = ssq; }
    __syncthreads();
    sum = red[0] + red[1] + red[2] + red[3];
    ssq = red[4] + red[5] + red[6] + red[7];
    const float mu = sum * (1.f / HID);
    const float var = ssq * (1.f / HID) - mu * mu;
    const float rstd = rsqrtf(var + LN_EPS);

    const float4 g = ((const float4*)gamma)[t];
    const float4 be = ((const float4*)beta)[t];
    float4 o;
    o.x = (yv.x - mu) * rstd * g.x + be.x;
    o.y = (yv.y - mu) * rstd * g.y + be.y;
    o.z = (yv.z - mu) * rstd * g.z + be.z;
    o.w = (yv.w - mu) * rstd * g.w + be.w;
    ((float4*)(out + (size_t)r * HID))[t] = o;
}

// ---------------------------------------------------------------------------
extern "C" void kernel_launch(void* const* d_in, const int* in_sizes, int n_in,
                              void* d_out, int out_size, void* d_ws, size_t ws_size,
                              hipStream_t stream) {
    const float* x     = (const float*)d_in[0];
    const float* xm    = (const float*)d_in[1];
    const float* kc    = (const float*)d_in[2];
    const float* vc    = (const float*)d_in[3];
    const float* wq    = (const float*)d_in[4];
    const float* bq    = (const float*)d_in[5];
    const float* wo    = (const float*)d_in[6];
    const float* bo    = (const float*)d_in[7];
    const float* gamma = (const float*)d_in[8];
    const float* beta  = (const float*)d_in[9];
    float* out = (float*)d_out;

    float* ws = (float*)d_ws;
    float* q_ws   = ws;                                               // 65536
    float* o_ws   = q_ws + ROWS * HID;                                // 2097152
    float* ml_ws  = o_ws + (size_t)BATCH * NHEADS * NCHUNK * SQ * HD; // 65536
    float* ctx_ws = ml_ws + BATCH * NHEADS * NCHUNK * SQ * 2;         // 65536
    float* y_ws   = ctx_ws + ROWS * HID;                              // 65536

    qrope_gemv<<<dim3(256), 256, 0, stream>>>(x, xm, wq, bq, q_ws);
    attn_partial<<<dim3(NCHUNK, NHEADS, BATCH), 256, 0, stream>>>(q_ws, kc, vc, o_ws, ml_ws);
    attn_combine<<<dim3(256), 256, 0, stream>>>(o_ws, ml_ws, ctx_ws);
    out_gemv<<<dim3(256), 256, 0, stream>>>(ctx_ws, x, wo, bo, y_ws);
    ln_kernel<<<dim3(ROWS), 256, 0, stream>>>(y_ws, gamma, beta, out);
}

// Round 6
// 150.402 us; speedup vs baseline: 3.6030x; 3.6030x over previous
//
#include <hip/hip_runtime.h>
#include <math.h>

#define NHEADS 16
#define HD 64
#define HID 1024
#define BATCH 4
#define SQ 16
#define SKV 8192
#define ROWS 64     // B*SQ
#define NCHUNK 32
#define CHUNK 256   // keys per attn block (64 per wave)
#define LN_EPS 1e-5f

// ---------------------------------------------------------------------------
// DPP rotate-reduce: sum across the 16 lanes of each 16-lane DPP row.
// ---------------------------------------------------------------------------
__device__ __forceinline__ float rowsum16(float x) {
    union fi { float f; int i; };
    fi a, b;
    a.f = x;
    b.i = __builtin_amdgcn_update_dpp(0, a.i, 0x128, 0xf, 0xf, true); a.f += b.f; // ror 8
    b.i = __builtin_amdgcn_update_dpp(0, a.i, 0x124, 0xf, 0xf, true); a.f += b.f; // ror 4
    b.i = __builtin_amdgcn_update_dpp(0, a.i, 0x122, 0xf, 0xf, true); a.f += b.f; // ror 2
    b.i = __builtin_amdgcn_update_dpp(0, a.i, 0x121, 0xf, 0xf, true); a.f += b.f; // ror 1
    return a.f;
}

// ---------------------------------------------------------------------------
// Kernel 1: q = RoPE(x @ wq^T + bq) -> [B][NH][SQ][HD]  (unchanged)
// ---------------------------------------------------------------------------
__global__ __launch_bounds__(256) void qrope_gemv(
    const float* __restrict__ x,
    const float* __restrict__ xm,
    const float* __restrict__ wq,
    const float* __restrict__ bq,
    float* __restrict__ qout)
{
    __shared__ float xs[ROWS * 256];
    __shared__ float sqx[4][ROWS];

    const int t = threadIdx.x, w = t >> 6, l = t & 63;
    const int cb = blockIdx.x;
    const int h = cb >> 4;
    const int sub = cb & 15;
    const int dd = sub * 2 + (w & 1) + (w >> 1) * 32;
    const int j = h * 64 + dd;

    float acc[ROWS];
    #pragma unroll
    for (int r = 0; r < ROWS; ++r) acc[r] = 0.f;

    const float4* x4 = (const float4*)x;
    const float4* w4 = (const float4*)(wq + (size_t)j * HID);
    float4* xs4 = (float4*)xs;

    for (int ck = 0; ck < 4; ++ck) {
        __syncthreads();
        #pragma unroll
        for (int p = 0; p < 16; ++p) {
            const int idx = t + p * 256;
            const int r = idx >> 6, c = idx & 63;
            xs4[idx] = x4[(size_t)r * 256 + ck * 64 + c];
        }
        __syncthreads();

        const float4 wf = w4[ck * 64 + l];
        #pragma unroll
        for (int r = 0; r < ROWS; ++r) {
            const float4 xf = xs4[r * 64 + l];
            acc[r] += wf.x * xf.x + wf.y * xf.y + wf.z * xf.z + wf.w * xf.w;
        }
    }

    #pragma unroll
    for (int r = 0; r < ROWS; ++r) {
        float a = acc[r];
        #pragma unroll
        for (int off = 32; off; off >>= 1) a += __shfl_xor(a, off);
        acc[r] = a;
    }
    float val = acc[0];
    #pragma unroll
    for (int r = 1; r < ROWS; ++r) val = (l == r) ? acc[r] : val;
    val += bq[j];

    sqx[w][l] = val;
    __syncthreads();

    const int r = l;
    float outv;
    if (w < 2) {
        const float q0 = sqx[w][l];
        const float q1 = sqx[w + 2][l];
        const float sn = xm[r * 64 + dd];
        const float co = xm[r * 64 + 32 + dd];
        outv = q0 * co - q1 * sn;
    } else {
        const int d2 = dd - 32;
        const float q0 = sqx[w - 2][l];
        const float q1 = sqx[w][l];
        const float sn = xm[r * 64 + d2];
        const float co = xm[r * 64 + 32 + d2];
        outv = q0 * sn + q1 * co;
    }
    const int b = r >> 4, s_ = r & 15;
    qout[(((size_t)b * NHEADS + h) * SQ + s_) * HD + dd] = outv;
}

// ---------------------------------------------------------------------------
// Kernel 2: split-K partial attention, zero redundant KV reads.
// grid (NCHUNK, NH, B) = 2048 blocks, 256 threads (4 waves).
// Wave w owns keys [64w, 64w+64) of the chunk and processes ALL 16 q-rows.
// Lane l = (kg = l>>4, dq = l&15): dims 4dq..4dq+3, keys {16st + 4ki + kg}.
// Shared max per 4-row batch (2 shfls/batch). One LDS merge per block.
// ---------------------------------------------------------------------------
__global__ __launch_bounds__(256, 2) void attn_partial(
    const float* __restrict__ q,     // [B][NH][SQ][HD]
    const float* __restrict__ kc,    // [B][NH][SKV][HD]
    const float* __restrict__ vc,    // [B][NH][SKV][HD]
    float* __restrict__ o_part,      // [B*NH][NCHUNK][SQ][HD]
    float* __restrict__ ml_part)     // [B*NH][NCHUNK][SQ][2]
{
    __shared__ float oL[4][SQ][64];  // 16 KB: per-wave partial O
    __shared__ float mLs[4][4];      // per-wave, per-row-batch max
    __shared__ float lLs[4][SQ];     // per-wave, per-row lsum

    const int chunk = blockIdx.x, h = blockIdx.y, b = blockIdx.z;
    const int bh = b * NHEADS + h;
    const int t = threadIdx.x, w = t >> 6, l = t & 63;
    const int kg = l >> 4, dq = l & 15;

    const float4* qb = (const float4*)(q + (size_t)bh * SQ * HD);
    const size_t kvbase = (size_t)bh * SKV * HD + ((size_t)chunk * CHUNK + w * 64) * HD;
    const float4* kb = (const float4*)(kc + kvbase);
    const float4* vb = (const float4*)(vc + kvbase);

    float4 qreg[SQ];
    #pragma unroll
    for (int r = 0; r < SQ; ++r) qreg[r] = qb[r * 16 + dq];

    float4 oacc[SQ];
    float lsum[SQ];
    float m[4];
    #pragma unroll
    for (int r = 0; r < SQ; ++r) { oacc[r] = make_float4(0.f, 0.f, 0.f, 0.f); lsum[r] = 0.f; }
    #pragma unroll
    for (int rb = 0; rb < 4; ++rb) m[rb] = -INFINITY;

    #pragma unroll 1
    for (int st = 0; st < 4; ++st) {   // 16 keys per subtile, 64 total per wave
        float4 kreg[4], vreg[4];
        #pragma unroll
        for (int ki = 0; ki < 4; ++ki) {
            const int key = st * 16 + ki * 4 + kg;
            kreg[ki] = kb[key * 16 + dq];
            vreg[ki] = vb[key * 16 + dq];
        }

        #pragma unroll
        for (int rb = 0; rb < 4; ++rb) {   // 4-row batches
            float pk[4][4];
            #pragma unroll
            for (int rr = 0; rr < 4; ++rr) {
                const float4 qv = qreg[rb * 4 + rr];
                #pragma unroll
                for (int ki = 0; ki < 4; ++ki) {
                    const float d = kreg[ki].x * qv.x + kreg[ki].y * qv.y
                                  + kreg[ki].z * qv.z + kreg[ki].w * qv.w;
                    pk[rr][ki] = rowsum16(d);   // dq lanes now all hold s[row][key]
                }
            }

            // shared max over the batch (16 values in-lane, then cross-kg)
            float bmax = pk[0][0];
            #pragma unroll
            for (int rr = 0; rr < 4; ++rr) {
                #pragma unroll
                for (int ki = 0; ki < 4; ++ki) bmax = fmaxf(bmax, pk[rr][ki]);
            }
            bmax = fmaxf(bmax, __shfl_xor(bmax, 16));
            bmax = fmaxf(bmax, __shfl_xor(bmax, 32));

            if (bmax > m[rb]) {   // wave-uniform branch
                const float sc = __expf(m[rb] - bmax);   // first time: exp(-inf)=0
                m[rb] = bmax;
                #pragma unroll
                for (int rr = 0; rr < 4; ++rr) {
                    const int r = rb * 4 + rr;
                    lsum[r] *= sc;
                    oacc[r].x *= sc; oacc[r].y *= sc; oacc[r].z *= sc; oacc[r].w *= sc;
                }
            }

            #pragma unroll
            for (int rr = 0; rr < 4; ++rr) {
                const int r = rb * 4 + rr;
                #pragma unroll
                for (int ki = 0; ki < 4; ++ki) {
                    const float pe = __expf(pk[rr][ki] - m[rb]);
                    lsum[r] += pe;
                    oacc[r].x += pe * vreg[ki].x;
                    oacc[r].y += pe * vreg[ki].y;
                    oacc[r].z += pe * vreg[ki].z;
                    oacc[r].w += pe * vreg[ki].w;
                }
            }
        }
    }

    // ---- reduce over the 4 kg groups (lane bits 4,5)
    #pragma unroll
    for (int r = 0; r < SQ; ++r) {
        #pragma unroll
        for (int off = 16; off <= 32; off <<= 1) {
            oacc[r].x += __shfl_xor(oacc[r].x, off);
            oacc[r].y += __shfl_xor(oacc[r].y, off);
            oacc[r].z += __shfl_xor(oacc[r].z, off);
            oacc[r].w += __shfl_xor(oacc[r].w, off);
            lsum[r] += __shfl_xor(lsum[r], off);
        }
    }

    // ---- stage per-wave partials to LDS
    if (kg == 0) {
        #pragma unroll
        for (int r = 0; r < SQ; ++r)
            *((float4*)&oL[w][r][dq * 4]) = oacc[r];
    }
    if (l == 0) {
        #pragma unroll
        for (int r = 0; r < SQ; ++r) lLs[w][r] = lsum[r];
        #pragma unroll
        for (int rb = 0; rb < 4; ++rb) mLs[w][rb] = m[rb];
    }
    __syncthreads();

    // ---- merge 4 waves: thread t -> (row r = t>>4, dim-quad dq2 = t&15)
    {
        const int r = t >> 4, dq2 = t & 15, rb = r >> 2;
        const float M = fmaxf(fmaxf(mLs[0][rb], mLs[1][rb]), fmaxf(mLs[2][rb], mLs[3][rb]));
        float L = 0.f;
        float4 O = make_float4(0.f, 0.f, 0.f, 0.f);
        #pragma unroll
        for (int ww = 0; ww < 4; ++ww) {
            const float sc = __expf(mLs[ww][rb] - M);
            L += lLs[ww][r] * sc;
            const float4 ov = *((const float4*)&oL[ww][r][dq2 * 4]);
            O.x += ov.x * sc; O.y += ov.y * sc; O.z += ov.z * sc; O.w += ov.w * sc;
        }
        ((float4*)(o_part + (((size_t)bh * NCHUNK + chunk) * SQ + r) * HD))[dq2] = O;
        if (dq2 == 0) {
            ml_part[(((size_t)bh * NCHUNK + chunk) * SQ + r) * 2 + 0] = M;
            ml_part[(((size_t)bh * NCHUNK + chunk) * SQ + r) * 2 + 1] = L;
        }
    }
}

// ---------------------------------------------------------------------------
// Kernel 3: combine partials -> ctx [64][1024]  (unchanged)
// ---------------------------------------------------------------------------
__global__ __launch_bounds__(256) void attn_combine(
    const float* __restrict__ o_part,
    const float* __restrict__ ml_part,
    float* __restrict__ ctx)
{
    __shared__ float mls[NCHUNK * 4 * 2];
    const int bh = blockIdx.x >> 2, qg = blockIdx.x & 3;
    const int b = bh >> 4, h = bh & 15;
    const int t = threadIdx.x;
    const int qi_l = t >> 6, d = t & 63;
    const int qi = qg * 4 + qi_l;

    mls[t] = ml_part[(((size_t)bh * NCHUNK + (t >> 3)) * SQ + qg * 4 + ((t >> 1) & 3)) * 2 + (t & 1)];
    __syncthreads();

    float M = -INFINITY;
    #pragma unroll
    for (int c = 0; c < NCHUNK; ++c) M = fmaxf(M, mls[(c * 4 + qi_l) * 2]);
    float L = 0.f, O = 0.f;
    #pragma unroll 4
    for (int c = 0; c < NCHUNK; ++c) {
        const float sc = __expf(mls[(c * 4 + qi_l) * 2] - M);
        L += mls[(c * 4 + qi_l) * 2 + 1] * sc;
        O += o_part[(((size_t)bh * NCHUNK + c) * SQ + qi) * HD + d] * sc;
    }
    ctx[((size_t)(b * SQ + qi)) * HID + h * HD + d] = O / L;
}

// ---------------------------------------------------------------------------
// Kernel 4: y = x + ctx @ wo^T + bo  (unchanged)
// ---------------------------------------------------------------------------
__global__ __launch_bounds__(256) void out_gemv(
    const float* __restrict__ ctx,
    const float* __restrict__ x,
    const float* __restrict__ wo,
    const float* __restrict__ bo,
    float* __restrict__ y)
{
    __shared__ float xs[ROWS * 256];

    const int t = threadIdx.x, w = t >> 6, l = t & 63;
    const int j = blockIdx.x * 4 + w;

    float acc[ROWS];
    #pragma unroll
    for (int r = 0; r < ROWS; ++r) acc[r] = 0.f;

    const float4* c4 = (const float4*)ctx;
    const float4* w4 = (const float4*)(wo + (size_t)j * HID);
    float4* xs4 = (float4*)xs;

    for (int ck = 0; ck < 4; ++ck) {
        __syncthreads();
        #pragma unroll
        for (int p = 0; p < 16; ++p) {
            const int idx = t + p * 256;
            const int r = idx >> 6, c = idx & 63;
            xs4[idx] = c4[(size_t)r * 256 + ck * 64 + c];
        }
        __syncthreads();

        const float4 wf = w4[ck * 64 + l];
        #pragma unroll
        for (int r = 0; r < ROWS; ++r) {
            const float4 xf = xs4[r * 64 + l];
            acc[r] += wf.x * xf.x + wf.y * xf.y + wf.z * xf.z + wf.w * xf.w;
        }
    }

    #pragma unroll
    for (int r = 0; r < ROWS; ++r) {
        float a = acc[r];
        #pragma unroll
        for (int off = 32; off; off >>= 1) a += __shfl_xor(a, off);
        acc[r] = a;
    }
    float val = acc[0];
    #pragma unroll
    for (int r = 1; r < ROWS; ++r) val = (l == r) ? acc[r] : val;

    val += bo[j] + x[(size_t)l * HID + j];
    y[(size_t)l * HID + j] = val;
}

// ---------------------------------------------------------------------------
// Kernel 5: out = LN(y) * gamma + beta  (unchanged)
// ---------------------------------------------------------------------------
__global__ __launch_bounds__(256) void ln_kernel(
    const float* __restrict__ y,
    const float* __restrict__ gamma,
    const float* __restrict__ beta,
    float* __restrict__ out)
{
    __shared__ float red[8];
    const int r = blockIdx.x, t = threadIdx.x;
    const int w = t >> 6, l = t & 63;

    const float4 yv = ((const float4*)(y + (size_t)r * HID))[t];
    float sum = yv.x + yv.y + yv.z + yv.w;
    float ssq = yv.x * yv.x + yv.y * yv.y + yv.z * yv.z + yv.w * yv.w;
    #pragma unroll
    for (int off = 32; off; off >>= 1) {
        sum += __shfl_xor(sum, off);
        ssq += __shfl_xor(ssq, off);
    }
    if (l == 0) { red[w] = sum; red[4 + w] = ssq; }
    __syncthreads();
    sum = red[0] + red[1] + red[2] + red[3];
    ssq = red[4] + red[5] + red[6] + red[7];
    const float mu = sum * (1.f / HID);
    const float var = ssq * (1.f / HID) - mu * mu;
    const float rstd = rsqrtf(var + LN_EPS);

    const float4 g = ((const float4*)gamma)[t];
    const float4 be = ((const float4*)beta)[t];
    float4 o;
    o.x = (yv.x - mu) * rstd * g.x + be.x;
    o.y = (yv.y - mu) * rstd * g.y + be.y;
    o.z = (yv.z - mu) * rstd * g.z + be.z;
    o.w = (yv.w - mu) * rstd * g.w + be.w;
    ((float4*)(out + (size_t)r * HID))[t] = o;
}

// ---------------------------------------------------------------------------
extern "C" void kernel_launch(void* const* d_in, const int* in_sizes, int n_in,
                              void* d_out, int out_size, void* d_ws, size_t ws_size,
                              hipStream_t stream) {
    const float* x     = (const float*)d_in[0];
    const float* xm    = (const float*)d_in[1];
    const float* kc    = (const float*)d_in[2];
    const float* vc    = (const float*)d_in[3];
    const float* wq    = (const float*)d_in[4];
    const float* bq    = (const float*)d_in[5];
    const float* wo    = (const float*)d_in[6];
    const float* bo    = (const float*)d_in[7];
    const float* gamma = (const float*)d_in[8];
    const float* beta  = (const float*)d_in[9];
    float* out = (float*)d_out;

    float* ws = (float*)d_ws;
    float* q_ws   = ws;                                               // 65536
    float* o_ws   = q_ws + ROWS * HID;                                // 2097152
    float* ml_ws  = o_ws + (size_t)BATCH * NHEADS * NCHUNK * SQ * HD; // 65536
    float* ctx_ws = ml_ws + BATCH * NHEADS * NCHUNK * SQ * 2;         // 65536
    float* y_ws   = ctx_ws + ROWS * HID;                              // 65536

    qrope_gemv<<<dim3(256), 256, 0, stream>>>(x, xm, wq, bq, q_ws);
    attn_partial<<<dim3(NCHUNK, NHEADS, BATCH), 256, 0, stream>>>(q_ws, kc, vc, o_ws, ml_ws);
    attn_combine<<<dim3(256), 256, 0, stream>>>(o_ws, ml_ws, ctx_ws);
    out_gemv<<<dim3(256), 256, 0, stream>>>(ctx_ws, x, wo, bo, y_ws);
    ln_kernel<<<dim3(ROWS), 256, 0, stream>>>(y_ws, gamma, beta, out);
}